// Round 12
// baseline (253.448 us; speedup 1.0000x reference)
//
#include <hip/hip_runtime.h>
#include <math.h>

// SCARF KNN+LBS-blend kernel.  B=1, N=32768, V=10475, K=6, J=55.
// out = [ xyz_dist (N floats) | xyz_transform (N*16 floats) ]
//
// NUMERICS (verified rounds 3-7,9-11): x4-SCALED domain, coords doubled
// (exact). Exact reference distance: d = fmaf(-2, C', q'+t2'),
// C' = fma(Pz,Z, fma(Py,Y, Px*X)). Screening in SHIFTED space
// d' = fmaf(-2, C', t2') with |d_exact - (q'+d')| <= eps ~ 2.2e-5; gate
// margin GMARG = 2.5e-4 >> 2*eps guarantees every exact-top-6 element
// passes (order stats of pointwise-eps-close sets differ <= eps).
// Survivors recompute the BIT-EXACT reference d. Unscale 0.25f at outputs.
// Contraction off globally.
//
// ROUND 12 — SINGLE gated sweep (deletes one full template scan):
//  * v6(prefix) >= v6(full), so a gate built from ANY scanned prefix is a
//    valid superset gate. Init: min-scan tiles 0-1 (1024 verts) -> U.
//    Then one sweep over all 21 tiles: gated pushes + continued lane-min
//    accumulation; U re-tightened (THRESH6, 6th-distinct of lane minima
//    + margin) after tiles 4,7,10,13,16,19.
//  * expected pushes ~27/point (512*6*sum(1/prefix)); CAP 64 -> overflow
//    z ~ 6. Guarded push (k<CAP) cannot corrupt.
//  * TILE 512 ping-pong + CAP-64 buffers = 34.4 KB LDS -> 4 blocks/CU.
//  * staging/syncs halved vs two-pass; rebuild/conf/epilogue verbatim r11.
#pragma clang fp contract(off)

#define NPTS  32768
#define NV    10475
#define JW    55
#define TILE  512
#define NT    21          // 21*512 = 10752 >= NV (tail sentinel-padded)
#define BLOCK 256
#define R     8           // points per wave
#define PPB   32          // (BLOCK/64) waves * R -> grid 1024 (4 blocks/CU)
#define CAP   64          // survivor buffer per point (mean ~27, z~6)
#define FINF  3.4e38f
#define GMARG 0.00025f    // >> 2*eps (eps ~ 2.2e-5, scaled domain)

#define FOR8(M) M(0) M(1) M(2) M(3) M(4) M(5) M(6) M(7)

// lexicographic (dist, idx) insert (jax top_k tie rule: lower idx wins on ties)
#define LTL(dd, vv, D, I) ((dd) < (D) || ((dd) == (D) && (vv) < (I)))
#define INSL6(dd, vv, D0,I0,D1,I1,D2,I2,D3,I3,D4,I4,D5,I5) \
  if (LTL(dd, vv, D5, I5)) { \
    if (LTL(dd, vv, D4, I4)) { D5=D4; I5=I4; \
      if (LTL(dd, vv, D3, I3)) { D4=D3; I4=I3; \
        if (LTL(dd, vv, D2, I2)) { D3=D2; I3=I2; \
          if (LTL(dd, vv, D1, I1)) { D2=D1; I2=I1; \
            if (LTL(dd, vv, D0, I0)) { D1=D0; I1=I0; D0=(dd); I0=(vv); } \
            else { D1=(dd); I1=(vv); } \
          } else { D2=(dd); I2=(vv); } \
        } else { D3=(dd); I3=(vv); } \
      } else { D4=(dd); I4=(vv); } \
    } else { D5=(dd); I5=(vv); } \
  }

__global__ __launch_bounds__(BLOCK, 4)
void scarf_knn_lbs(const float* __restrict__ lbs,   // [NV][JW]
                   const float* __restrict__ vtf,   // [NV][16]
                   const float* __restrict__ pts,   // [NPTS][3]
                   const float* __restrict__ tpl,   // [NV][3]
                   float* __restrict__ out_dist,    // [NPTS]
                   float* __restrict__ out_tf)      // [NPTS][16]
{
    __shared__ float4 s_tile[2][TILE];   // 16,384 B ping-pong
    __shared__ float  s_bd[PPB][CAP];    //  8,192 B
    __shared__ int    s_bi[PPB][CAP];    //  8,192 B
    __shared__ int    s_cnt[PPB];        //    128 B
    __shared__ float  s_td[PPB][6];      //    768 B
    __shared__ int    s_ti[PPB][6];      //    768 B   (34,432 B total)

    const int tid = threadIdx.x;
    const int h   = tid & 63;            // lane in wave
    const int w   = tid >> 6;            // wave 0..3
    const int lp  = w * R;               // wave's base local point
    const int p0  = blockIdx.x * PPB + lp;

    if (tid < PPB) s_cnt[tid] = 0;

    // ---- 8 query points per wave, doubled coords (exact), q' = 4*p2_ref ----
    #define DECLP(r) \
      const float Px##r = 2.0f * pts[(p0+(r))*3+0]; \
      const float Py##r = 2.0f * pts[(p0+(r))*3+1]; \
      const float Pz##r = 2.0f * pts[(p0+(r))*3+2]; \
      const float q##r  = (Px##r*Px##r + Py##r*Py##r) + Pz##r*Pz##r;
    FOR8(DECLP)

    // staging: thread loads verts j = t*TILE + k*BLOCK + tid, k=0,1
    float gx[2], gy[2], gz[2];
    #define STAGE_ISSUE(t_) { \
      _Pragma("unroll") \
      for (int k = 0; k < 2; ++k) { \
        const int j = (t_) * TILE + k * BLOCK + tid; \
        if (j < NV) { gx[k] = tpl[j*3+0]; gy[k] = tpl[j*3+1]; gz[k] = tpl[j*3+2]; } \
        else        { gx[k] = 1.0e6f;    gy[k] = 1.0e6f;    gz[k] = 1.0e6f;    } } }
    // slot k*BLOCK+tid: 16B lane stride -> conflict-free b128 writes
    #define STAGE_WRITE(dst_) { \
      _Pragma("unroll") \
      for (int k = 0; k < 2; ++k) { \
        const float X = gx[k]+gx[k], Y = gy[k]+gy[k], Z = gz[k]+gz[k]; \
        s_tile[dst_][k * BLOCK + tid] = make_float4(X, Y, Z, (X*X + Y*Y) + Z*Z); } }

    // per-lane running minima of d' (shifted space)
    #define DECLM(r) float m##r = FINF;
    FOR8(DECLM)

    // min-only paired eval (init pass)
    #define EVI(r) { \
      const float Ca = fmaf(Pz##r, ta.z, fmaf(Py##r, ta.y, Px##r * ta.x)); \
      const float da = fmaf(-2.0f, Ca, ta.w); \
      const float Cb = fmaf(Pz##r, tb.z, fmaf(Py##r, tb.y, Px##r * tb.x)); \
      const float db = fmaf(-2.0f, Cb, tb.w); \
      m##r = fminf(fminf(m##r, da), db); }

    // gated paired eval (main sweep): push bit-exact d on survive + min-track
    #define EVG(r) { \
      const float Ca = fmaf(Pz##r, ta.z, fmaf(Py##r, ta.y, Px##r * ta.x)); \
      const float da = fmaf(-2.0f, Ca, ta.w); \
      if (da <= U##r) { \
        const float de = fmaf(-2.0f, Ca, q##r + ta.w); \
        const int k = atomicAdd(&s_cnt[lp+(r)], 1); \
        if (k < CAP) { s_bd[lp+(r)][k] = fmaxf(de, 0.0f); s_bi[lp+(r)][k] = ia; } } \
      const float Cb = fmaf(Pz##r, tb.z, fmaf(Py##r, tb.y, Px##r * tb.x)); \
      const float db = fmaf(-2.0f, Cb, tb.w); \
      if (db <= U##r) { \
        const float de = fmaf(-2.0f, Cb, q##r + tb.w); \
        const int k = atomicAdd(&s_cnt[lp+(r)], 1); \
        if (k < CAP) { s_bd[lp+(r)][k] = fmaxf(de, 0.0f); s_bi[lp+(r)][k] = ib; } } \
      m##r = fminf(fminf(m##r, da), db); }

    // gate update: 6th smallest DISTINCT of 64 lane minima + margin
    #define UPDT(r) { \
      float v = m##r; float M; \
      _Pragma("unroll") \
      for (int rep = 0; rep < 6; ++rep) { \
        M = v; \
        M = fminf(M, __shfl_xor(M, 1)); \
        M = fminf(M, __shfl_xor(M, 2)); \
        M = fminf(M, __shfl_xor(M, 4)); \
        M = fminf(M, __shfl_xor(M, 8)); \
        M = fminf(M, __shfl_xor(M, 16)); \
        M = fminf(M, __shfl_xor(M, 32)); \
        if (rep < 5) v = (v == M) ? FINF : v; \
      } \
      U##r = M + GMARG; }

    // ---- stage tiles 0,1; init min-scan over them (1024 verts) ----
    STAGE_ISSUE(0); STAGE_WRITE(0);
    STAGE_ISSUE(1); STAGE_WRITE(1);
    __syncthreads();
    #pragma unroll
    for (int b = 0; b < 2; ++b) {
        const float4* bp = s_tile[b];
        #pragma unroll
        for (int itp = 0; itp < 4; ++itp) {
            const float4 ta = bp[(2*itp    ) * 64 + h];
            const float4 tb = bp[(2*itp + 1) * 64 + h];
            FOR8(EVI)
        }
    }

    // ---- initial gates from the 1024-vert prefix ----
    #define DECLU(r) float U##r; UPDT(r);
    FOR8(DECLU)

    // ---- single gated sweep over all 21 tiles (re-scans 0,1: no dup pushes,
    //      init pushed nothing) ----
    for (int t = 0; t < NT; ++t) {
        if (t >= 1 && t + 1 < NT) STAGE_ISSUE(t + 1);
        const float4* bp = s_tile[t & 1];
        #pragma unroll
        for (int itp = 0; itp < 4; ++itp) {
            const int ia = t * TILE + (2*itp) * 64 + h;
            const int ib = ia + 64;
            const float4 ta = bp[(2*itp    ) * 64 + h];
            const float4 tb = bp[(2*itp + 1) * 64 + h];
            FOR8(EVG)
        }
        if (t >= 1 && t + 1 < NT) STAGE_WRITE((t + 1) & 1);
        __syncthreads();
        if (t >= 4 && t % 3 == 1) { FOR8(UPDT) }   // t = 4,7,10,13,16,19
    }
    // survivor buffers are wave-private from here on (same-wave LDS ordering)

    // ---- exact top-6 per point, built by lanes h<8, published to LDS ----
    if (h < 8) {
        const int lpr = lp + h;
        float D0=FINF,D1=FINF,D2=FINF,D3=FINF,D4=FINF,D5=FINF;
        int   I0=-1,I1=-1,I2=-1,I3=-1,I4=-1,I5=-1;
        const int cc = s_cnt[lpr];
        const int c  = (cc < CAP) ? cc : CAP;
        for (int k = 0; k < c; ++k) {
            const float dd = s_bd[lpr][k]; const int vv = s_bi[lpr][k];
            INSL6(dd, vv, D0,I0,D1,I1,D2,I2,D3,I3,D4,I4,D5,I5);
        }
        s_td[lpr][0]=D0; s_td[lpr][1]=D1; s_td[lpr][2]=D2;
        s_td[lpr][3]=D3; s_td[lpr][4]=D4; s_td[lpr][5]=D5;
        s_ti[lpr][0]=I0; s_ti[lpr][1]=I1; s_ti[lpr][2]=I2;
        s_ti[lpr][3]=I3; s_ti[lpr][4]=I4; s_ti[lpr][5]=I5;
    }

    // ---- confidence: 8 lanes cooperate per point (coalesced + tree reduce) ----
    {
        const int r  = h >> 3;            // point 0..7
        const int l  = h & 7;             // sub-lane 0..7
        const int lpr = lp + r;
        const int i0 = s_ti[lpr][0];
        const int i1 = s_ti[lpr][1], i2 = s_ti[lpr][2], i3 = s_ti[lpr][3];
        const int i4 = s_ti[lpr][4], i5 = s_ti[lpr][5];
        float s1 = 0.0f, s2 = 0.0f, s3 = 0.0f, s4 = 0.0f, s5 = 0.0f;
        for (int j = l; j < JW; j += 8) {
            const float w0 = lbs[(long)i0 * JW + j];
            s1 += fabsf(lbs[(long)i1 * JW + j] - w0);
            s2 += fabsf(lbs[(long)i2 * JW + j] - w0);
            s3 += fabsf(lbs[(long)i3 * JW + j] - w0);
            s4 += fabsf(lbs[(long)i4 * JW + j] - w0);
            s5 += fabsf(lbs[(long)i5 * JW + j] - w0);
        }
        s1 += __shfl_xor(s1,1); s1 += __shfl_xor(s1,2); s1 += __shfl_xor(s1,4);
        s2 += __shfl_xor(s2,1); s2 += __shfl_xor(s2,2); s2 += __shfl_xor(s2,4);
        s3 += __shfl_xor(s3,1); s3 += __shfl_xor(s3,2); s3 += __shfl_xor(s3,4);
        s4 += __shfl_xor(s4,1); s4 += __shfl_xor(s4,2); s4 += __shfl_xor(s4,4);
        s5 += __shfl_xor(s5,1); s5 += __shfl_xor(s5,2); s5 += __shfl_xor(s5,4);
        const float sv = (l==0)?s1:(l==1)?s2:(l==2)?s3:(l==3)?s4:s5;
        const bool pred = (l < 5) && (expf(-sv / 0.02f) > 0.9f);
        const unsigned long long bal = __ballot(pred);

        // ---- outputs: lane handles (point (h>>4)+4t, elem h&15), t=0,1 ----
        #pragma unroll
        for (int t = 0; t < 2; ++t) {
            const int re  = (h >> 4) + 4 * t;
            const int e   = h & 15;
            const int lpe = lp + re;
            const int P   = p0 + re;
            const unsigned mr = (unsigned)(bal >> (re * 8)) & 31u;

            // unscale: 0.25f * (4*dd_ref) = dd_ref exactly
            const float d0 = 0.25f * s_td[lpe][0], d1 = 0.25f * s_td[lpe][1];
            const float d2 = 0.25f * s_td[lpe][2], d3 = 0.25f * s_td[lpe][3];
            const float d4 = 0.25f * s_td[lpe][4], d5 = 0.25f * s_td[lpe][5];
            const int   j0 = s_ti[lpe][0], j1 = s_ti[lpe][1], j2 = s_ti[lpe][2];
            const int   j3 = s_ti[lpe][3], j4 = s_ti[lpe][4], j5 = s_ti[lpe][5];

            const float w0 = expf(-d0);
            const float w1 = (mr & 1u)  ? expf(-d1) : 0.0f;
            const float w2 = (mr & 2u)  ? expf(-d2) : 0.0f;
            const float w3 = (mr & 4u)  ? expf(-d3) : 0.0f;
            const float w4 = (mr & 8u)  ? expf(-d4) : 0.0f;
            const float w5 = (mr & 16u) ? expf(-d5) : 0.0f;
            const float inv = 1.0f / (w0 + w1 + w2 + w3 + w4 + w5);
            const float n0 = w0*inv, n1 = w1*inv, n2 = w2*inv;
            const float n3 = w3*inv, n4 = w4*inv, n5 = w5*inv;

            if (e == 0)
                out_dist[P] = n0*d0 + n1*d1 + n2*d2 + n3*d3 + n4*d4 + n5*d5;

            float acc = n0 * vtf[j0*16 + e];
            acc = fmaf(n1, vtf[j1*16 + e], acc);
            acc = fmaf(n2, vtf[j2*16 + e], acc);
            acc = fmaf(n3, vtf[j3*16 + e], acc);
            acc = fmaf(n4, vtf[j4*16 + e], acc);
            acc = fmaf(n5, vtf[j5*16 + e], acc);
            out_tf[P*16 + e] = acc;
        }
    }
}

extern "C" void kernel_launch(void* const* d_in, const int* in_sizes, int n_in,
                              void* d_out, int out_size, void* d_ws, size_t ws_size,
                              hipStream_t stream) {
    const float* lbs = (const float*)d_in[0];   // [10475][55]
    const float* vtf = (const float*)d_in[1];   // [10475][4][4]
    const float* pts = (const float*)d_in[2];   // [32768][3]
    const float* tpl = (const float*)d_in[3];   // [10475][3]
    float* out = (float*)d_out;
    scarf_knn_lbs<<<NPTS / PPB, BLOCK, 0, stream>>>(lbs, vtf, pts, tpl, out, out + NPTS);
}

// Round 13
// 114.722 us; speedup vs baseline: 2.2092x; 2.2092x over previous
//
#include <hip/hip_runtime.h>
#include <math.h>

// SCARF KNN+LBS-blend kernel.  B=1, N=32768, V=10475, K=6, J=55.
// out = [ xyz_dist (N floats) | xyz_transform (N*16 floats) ]
//
// NUMERICS (verified rounds 3-7,9-11): x4-SCALED domain, coords doubled
// (exact). Exact reference distance: d = fmaf(-2, C', q'+t2'),
// C' = fma(Pz,Z, fma(Py,Y, Px*X)), X/Y/Z doubled template coords.
// Screening in SHIFTED space (no q-add). ROUND 13 layout: LDS stores
// s = (-2X, -2Y, -2Z, t2') so screening d' = fma(Pz,sz, fma(Py,sy,
// fma(Px,sx, t2'))) is a pure 3-fma chain; d' = 4*t2 - 8*(p.t), the same
// x4-shifted space as r11. |d' + q' - d_exact| <= eps ~ 1.5e-4 (scaled);
// GMARG = 1e-3 >> 2*eps guarantees every exact-top-6 element passes the
// gate (order stats of pointwise-eps-close sets differ <= eps). Survivors
// recover X = -0.5*sx (exact, power of 2) and recompute the BIT-EXACT
// reference d. Unscale 0.25f at outputs. Contraction off globally.
//
// ROUND 13 vs r11 (253us r12 reverted — spill-driven; WRITE_SIZE 296MB):
//  * R=4 points/wave (halves live state, ~45 VGPR: no spill) and
//    PPB=16 -> grid 2048 -> 8 blocks/CU (LDS 20.0 KB) = 2x occupancy.
//  * 3-fma screening eval (was 4 ops).
//  * Two-pass structure, staging, rebuild, conf, epilogue logic proven in
//    r10/r11; conf uses 16 lanes/point, epilogue is a single pass.
#pragma clang fp contract(off)

#define NPTS  32768
#define NV    10475
#define JW    55
#define TILE  512
#define NT    21          // 21*512 = 10752 >= NV (tail sentinel-padded)
#define BLOCK 256
#define R     4           // points per wave
#define PPB   16          // 4 waves * 4 points -> grid 2048 (8 blocks/CU)
#define CAP   22          // survivor buffer per point
#define FINF  3.4e38f
#define GMARG 0.001f      // >> 2*eps (eps ~ 1.5e-4, scaled domain)

#define FOR4(M) M(0) M(1) M(2) M(3)

// lexicographic (dist, idx) insert (jax top_k tie rule: lower idx wins on ties)
#define LTL(dd, vv, D, I) ((dd) < (D) || ((dd) == (D) && (vv) < (I)))
#define INSL6(dd, vv, D0,I0,D1,I1,D2,I2,D3,I3,D4,I4,D5,I5) \
  if (LTL(dd, vv, D5, I5)) { \
    if (LTL(dd, vv, D4, I4)) { D5=D4; I5=I4; \
      if (LTL(dd, vv, D3, I3)) { D4=D3; I4=I3; \
        if (LTL(dd, vv, D2, I2)) { D3=D2; I3=I2; \
          if (LTL(dd, vv, D1, I1)) { D2=D1; I2=I1; \
            if (LTL(dd, vv, D0, I0)) { D1=D0; I1=I0; D0=(dd); I0=(vv); } \
            else { D1=(dd); I1=(vv); } \
          } else { D2=(dd); I2=(vv); } \
        } else { D3=(dd); I3=(vv); } \
      } else { D4=(dd); I4=(vv); } \
    } else { D5=(dd); I5=(vv); } \
  }

__global__ __launch_bounds__(BLOCK, 6)
void scarf_knn_lbs(const float* __restrict__ lbs,   // [NV][JW]
                   const float* __restrict__ vtf,   // [NV][16]
                   const float* __restrict__ pts,   // [NPTS][3]
                   const float* __restrict__ tpl,   // [NV][3]
                   float* __restrict__ out_dist,    // [NPTS]
                   float* __restrict__ out_tf)      // [NPTS][16]
{
    __shared__ float4 s_tile[2][TILE];   // 16,384 B ping-pong
    __shared__ float  s_bd[PPB][CAP];    //  1,408 B
    __shared__ int    s_bi[PPB][CAP];    //  1,408 B
    __shared__ int    s_cnt[PPB];        //     64 B
    __shared__ float  s_td[PPB][6];      //    384 B
    __shared__ int    s_ti[PPB][6];      //    384 B   (~20.0 KB total)

    const int tid = threadIdx.x;
    const int h   = tid & 63;            // lane in wave
    const int w   = tid >> 6;            // wave 0..3
    const int lp  = w * R;               // wave's base local point
    const int p0  = blockIdx.x * PPB + lp;

    if (tid < PPB) s_cnt[tid] = 0;

    // ---- 4 query points per wave, doubled coords (exact), q' = 4*p2_ref ----
    #define DECLP(r) \
      const float Px##r = 2.0f * pts[(p0+(r))*3+0]; \
      const float Py##r = 2.0f * pts[(p0+(r))*3+1]; \
      const float Pz##r = 2.0f * pts[(p0+(r))*3+2]; \
      const float q##r  = (Px##r*Px##r + Py##r*Py##r) + Pz##r*Pz##r;
    FOR4(DECLP)

    // staging: thread loads verts j = t*TILE + k*BLOCK + tid, k=0,1
    float gx[2], gy[2], gz[2];
    #define STAGE_ISSUE(t_) { \
      _Pragma("unroll") \
      for (int k = 0; k < 2; ++k) { \
        const int j = (t_) * TILE + k * BLOCK + tid; \
        if (j < NV) { gx[k] = tpl[j*3+0]; gy[k] = tpl[j*3+1]; gz[k] = tpl[j*3+2]; } \
        else        { gx[k] = 1.0e6f;    gy[k] = 1.0e6f;    gz[k] = 1.0e6f;    } } }
    // store (-2X, -2Y, -2Z, t2'); X = doubled coord; t2' from doubled (exact).
    // slot k*BLOCK+tid: 16B lane stride -> conflict-free b128 writes.
    #define STAGE_WRITE(dst_) { \
      _Pragma("unroll") \
      for (int k = 0; k < 2; ++k) { \
        const float X = gx[k]+gx[k], Y = gy[k]+gy[k], Z = gz[k]+gz[k]; \
        s_tile[dst_][k * BLOCK + tid] = \
          make_float4(-(X+X), -(Y+Y), -(Z+Z), (X*X + Y*Y) + Z*Z); } }

    // ================= pass 1: per-lane min of d' (3-fma eval) =============
    #define DECLM(r) float m##r = FINF;
    FOR4(DECLM)

    #define EVP1(r) { \
      const float da = fmaf(Pz##r, ta.z, fmaf(Py##r, ta.y, fmaf(Px##r, ta.x, ta.w))); \
      const float db = fmaf(Pz##r, tb.z, fmaf(Py##r, tb.y, fmaf(Px##r, tb.x, tb.w))); \
      m##r = fminf(fminf(m##r, da), db); }

    STAGE_ISSUE(0); STAGE_WRITE(0); __syncthreads();
    for (int t = 0; t < NT; ++t) {
        if (t + 1 < NT) STAGE_ISSUE(t + 1);
        const float4* bp = s_tile[t & 1];
        #pragma unroll
        for (int itp = 0; itp < 4; ++itp) {
            const float4 ta = bp[(2*itp    ) * 64 + h];
            const float4 tb = bp[(2*itp + 1) * 64 + h];
            FOR4(EVP1)
        }
        if (t + 1 < NT) { STAGE_WRITE((t + 1) & 1); __syncthreads(); }
    }

    // ---- gate: 6th smallest DISTINCT of 64 lane minima (d'-space) + margin ----
    #define DECLT(r) float G##r; { \
      float v = m##r; float M; \
      _Pragma("unroll") \
      for (int rep = 0; rep < 6; ++rep) { \
        M = v; \
        M = fminf(M, __shfl_xor(M, 1)); \
        M = fminf(M, __shfl_xor(M, 2)); \
        M = fminf(M, __shfl_xor(M, 4)); \
        M = fminf(M, __shfl_xor(M, 8)); \
        M = fminf(M, __shfl_xor(M, 16)); \
        M = fminf(M, __shfl_xor(M, 32)); \
        if (rep < 5) v = (v == M) ? FINF : v; \
      } \
      G##r = M + GMARG; }
    FOR4(DECLT)

    __syncthreads();   // all waves done with buf0 before pass-2 restage

    // ================= pass 2: rescan; gate on d', push EXACT d ============
    #define EVP2(r) { \
      const float dp = fmaf(Pz##r, tv.z, fmaf(Py##r, tv.y, fmaf(Px##r, tv.x, tv.w))); \
      if (dp <= G##r) { \
        const float Xr = -0.5f * tv.x, Yr = -0.5f * tv.y, Zr = -0.5f * tv.z; \
        const float C  = fmaf(Pz##r, Zr, fmaf(Py##r, Yr, Px##r * Xr)); \
        const float de = fmaf(-2.0f, C, q##r + tv.w);  /* bit-exact reference */ \
        const int k = atomicAdd(&s_cnt[lp+(r)], 1); \
        if (k < CAP) { s_bd[lp+(r)][k] = fmaxf(de, 0.0f); s_bi[lp+(r)][k] = tb + it*64 + h; } } }

    STAGE_ISSUE(0); STAGE_WRITE(0); __syncthreads();
    for (int t = 0; t < NT; ++t) {
        if (t + 1 < NT) STAGE_ISSUE(t + 1);
        const float4* bp = s_tile[t & 1];
        const int tb = t * TILE;
        #pragma unroll
        for (int it = 0; it < 8; ++it) {
            const float4 tv = bp[it * 64 + h];
            FOR4(EVP2)
        }
        if (t + 1 < NT) { STAGE_WRITE((t + 1) & 1); __syncthreads(); }
    }
    // survivor buffers are wave-private from here on (same-wave LDS ordering)

    // ---- exact top-6 per point, built by lanes h<4, published to LDS ----
    if (h < R) {
        const int lpr = lp + h;
        float D0=FINF,D1=FINF,D2=FINF,D3=FINF,D4=FINF,D5=FINF;
        int   I0=-1,I1=-1,I2=-1,I3=-1,I4=-1,I5=-1;
        const int cc = s_cnt[lpr];
        const int c  = (cc < CAP) ? cc : CAP;
        for (int k = 0; k < c; ++k) {
            const float dd = s_bd[lpr][k]; const int vv = s_bi[lpr][k];
            INSL6(dd, vv, D0,I0,D1,I1,D2,I2,D3,I3,D4,I4,D5,I5);
        }
        s_td[lpr][0]=D0; s_td[lpr][1]=D1; s_td[lpr][2]=D2;
        s_td[lpr][3]=D3; s_td[lpr][4]=D4; s_td[lpr][5]=D5;
        s_ti[lpr][0]=I0; s_ti[lpr][1]=I1; s_ti[lpr][2]=I2;
        s_ti[lpr][3]=I3; s_ti[lpr][4]=I4; s_ti[lpr][5]=I5;
    }

    // ---- confidence: 16 lanes cooperate per point (coalesced + tree reduce) ----
    const int r  = h >> 4;            // point 0..3
    const int l  = h & 15;            // sub-lane 0..15
    const int lpr = lp + r;
    const int i0 = s_ti[lpr][0];
    const int i1 = s_ti[lpr][1], i2 = s_ti[lpr][2], i3 = s_ti[lpr][3];
    const int i4 = s_ti[lpr][4], i5 = s_ti[lpr][5];
    {
        float s1 = 0.0f, s2 = 0.0f, s3 = 0.0f, s4 = 0.0f, s5 = 0.0f;
        for (int j = l; j < JW; j += 16) {
            const float w0 = lbs[(long)i0 * JW + j];
            s1 += fabsf(lbs[(long)i1 * JW + j] - w0);
            s2 += fabsf(lbs[(long)i2 * JW + j] - w0);
            s3 += fabsf(lbs[(long)i3 * JW + j] - w0);
            s4 += fabsf(lbs[(long)i4 * JW + j] - w0);
            s5 += fabsf(lbs[(long)i5 * JW + j] - w0);
        }
        s1 += __shfl_xor(s1,1); s1 += __shfl_xor(s1,2); s1 += __shfl_xor(s1,4); s1 += __shfl_xor(s1,8);
        s2 += __shfl_xor(s2,1); s2 += __shfl_xor(s2,2); s2 += __shfl_xor(s2,4); s2 += __shfl_xor(s2,8);
        s3 += __shfl_xor(s3,1); s3 += __shfl_xor(s3,2); s3 += __shfl_xor(s3,4); s3 += __shfl_xor(s3,8);
        s4 += __shfl_xor(s4,1); s4 += __shfl_xor(s4,2); s4 += __shfl_xor(s4,4); s4 += __shfl_xor(s4,8);
        s5 += __shfl_xor(s5,1); s5 += __shfl_xor(s5,2); s5 += __shfl_xor(s5,4); s5 += __shfl_xor(s5,8);
        const float sv = (l==0)?s1:(l==1)?s2:(l==2)?s3:(l==3)?s4:s5;
        const bool pred = (l < 5) && (expf(-sv / 0.02f) > 0.9f);
        const unsigned long long bal = __ballot(pred);
        const unsigned mr = (unsigned)(bal >> (r * 16)) & 31u;

        // ---- outputs: lane (point r, elem l) -> coalesced 64B rows ----
        const int P = p0 + r;
        // unscale: 0.25f * (4*dd_ref) = dd_ref exactly
        const float d0 = 0.25f * s_td[lpr][0], d1 = 0.25f * s_td[lpr][1];
        const float d2 = 0.25f * s_td[lpr][2], d3 = 0.25f * s_td[lpr][3];
        const float d4 = 0.25f * s_td[lpr][4], d5 = 0.25f * s_td[lpr][5];

        const float w0 = expf(-d0);
        const float w1 = (mr & 1u)  ? expf(-d1) : 0.0f;
        const float w2 = (mr & 2u)  ? expf(-d2) : 0.0f;
        const float w3 = (mr & 4u)  ? expf(-d3) : 0.0f;
        const float w4 = (mr & 8u)  ? expf(-d4) : 0.0f;
        const float w5 = (mr & 16u) ? expf(-d5) : 0.0f;
        const float inv = 1.0f / (w0 + w1 + w2 + w3 + w4 + w5);
        const float n0 = w0*inv, n1 = w1*inv, n2 = w2*inv;
        const float n3 = w3*inv, n4 = w4*inv, n5 = w5*inv;

        if (l == 0)
            out_dist[P] = n0*d0 + n1*d1 + n2*d2 + n3*d3 + n4*d4 + n5*d5;

        float acc = n0 * vtf[i0*16 + l];
        acc = fmaf(n1, vtf[i1*16 + l], acc);
        acc = fmaf(n2, vtf[i2*16 + l], acc);
        acc = fmaf(n3, vtf[i3*16 + l], acc);
        acc = fmaf(n4, vtf[i4*16 + l], acc);
        acc = fmaf(n5, vtf[i5*16 + l], acc);
        out_tf[P*16 + l] = acc;
    }
}

extern "C" void kernel_launch(void* const* d_in, const int* in_sizes, int n_in,
                              void* d_out, int out_size, void* d_ws, size_t ws_size,
                              hipStream_t stream) {
    const float* lbs = (const float*)d_in[0];   // [10475][55]
    const float* vtf = (const float*)d_in[1];   // [10475][4][4]
    const float* pts = (const float*)d_in[2];   // [32768][3]
    const float* tpl = (const float*)d_in[3];   // [10475][3]
    float* out = (float*)d_out;
    scarf_knn_lbs<<<NPTS / PPB, BLOCK, 0, stream>>>(lbs, vtf, pts, tpl, out, out + NPTS);
}